// Round 18
// baseline (185.006 us; speedup 1.0000x reference)
//
#include <hip/hip_runtime.h>
#include <hip/hip_fp16.h>

#define N_NODES 50000
#define N_EDGES 800000
#define IN_DIM  64
#define OUT_DIM 32
#define NODES_PER_BIN 32
#define NBINS   1563                 // ceil(50000/32)
#define NCLS    8
#define CLS_CAP 128                  // per (bin,class): mean 64, +8 sigma; chaining backstops
#define BIN_SLOTS (NCLS * CLS_CAP)   // 1024
#define NCURS   (NBINS * NCLS)       // 12504
#define SCATTER_BLOCKS (N_EDGES / 256)            // 3125 (1 edge/thread)
#define FC_NODES_PER_BLOCK 16
#define FC_BLOCKS (N_NODES / FC_NODES_PER_BLOCK)  // 3125

// physical XCD id (gfx950: HW_REG_XCC_ID = hwreg 20; learn_hip m09)
__device__ __forceinline__ int get_xcc_id() {
  return (int)(__builtin_amdgcn_s_getreg(63508) & 7u);  // 20 | (31<<11)
}

// Fused K1 (R16/R17 config, unchanged): scatter blocks (1 edge/thread, XCC-id
// class + chaining, transposed cursors [cls][bin]) then fc blocks (16
// nodes/block, W column register-cached).
__global__ __launch_bounds__(256) void fused_fc_scatter_kernel(
    const float* __restrict__ h, const float* __restrict__ Wfc,
    const float* __restrict__ bfc, const float* __restrict__ Watt,
    const int* __restrict__ src, const int* __restrict__ dst,
    const float* __restrict__ weight,
    __half2* __restrict__ ezh2, float4* __restrict__ a_tab,
    int* __restrict__ cursor, unsigned int* __restrict__ payload) {
  __shared__ float Wl[IN_DIM * OUT_DIM];                    // 8 KB
  __shared__ float4 hs4[FC_NODES_PER_BLOCK * 2 * 16];       // 8 KB
  int t = threadIdx.x;

  if (blockIdx.x < SCATTER_BLOCKS) {
    int xcc = get_xcc_id();                  // wave-uniform
    int e = blockIdx.x * 256 + t;            // exact coverage
    int s = src[e], d = dst[e];
    float wv = weight[e];
    unsigned int rec = ((unsigned int)s << 16) | ((unsigned int)(d & 31) << 11) |
                       ((unsigned int)__float2int_rn(wv * 2047.0f) & 2047u);
    int bin = d >> 5;
    int c = xcc;
#pragma unroll
    for (int a = 0; a < NCLS; ++a) {
      int pos = atomicAdd(&cursor[c * NBINS + bin], 1);   // XCD-local line
      if (pos < CLS_CAP) {
        payload[(size_t)bin * BIN_SLOTS + c * CLS_CAP + pos] = rec;
        break;
      }
      c = (c + 1) & 7;                       // overflow chain: ~never taken
    }
    return;
  }

  // ---- fc role: 16 nodes per block ----
  int n0 = (blockIdx.x - SCATTER_BLOCKS) * FC_NODES_PER_BLOCK;
  for (int i = t; i < 512; i += 256)
    ((float4*)Wl)[i] = ((const float4*)Wfc)[i];
#pragma unroll
  for (int f = t; f < FC_NODES_PER_BLOCK * 2 * 16; f += 256) {
    int ns = f >> 5, sb = (f >> 4) & 1, i4 = f & 15;
    hs4[f] = ((const float4*)h)[((size_t)sb * N_NODES + (n0 + ns)) * 16 + i4];
  }
  __syncthreads();
  int w = t >> 6, lane = t & 63, o = lane & 31, b = lane >> 5;
  float wreg[IN_DIM];
#pragma unroll
  for (int i = 0; i < IN_DIM; ++i) wreg[i] = Wl[i * OUT_DIM + o];
  float bo = bfc[o];
  float wo1 = Watt[o], wo2 = Watt[OUT_DIM + o];
#pragma unroll
  for (int k = 0; k < 4; ++k) {
    int ns = w * 4 + k;
    int n = n0 + ns;
    float acc = bo;
#pragma unroll
    for (int i4 = 0; i4 < 16; ++i4) {
      float4 hv = hs4[(ns * 2 + b) * 16 + i4];   // wave-broadcast (2 addrs: free)
      acc = fmaf(hv.x, wreg[i4 * 4 + 0], acc);
      acc = fmaf(hv.y, wreg[i4 * 4 + 1], acc);
      acc = fmaf(hv.z, wreg[i4 * 4 + 2], acc);
      acc = fmaf(hv.w, wreg[i4 * 4 + 3], acc);
    }
    float ez = __expf(acc);
    float ezo = __shfl(ez, lane ^ 32, 64);       // partner batch's value
    if (b == 0) {
      __half2 hv2;
      hv2.x = __float2half(ez);
      hv2.y = __float2half(ezo);
      ezh2[(size_t)n * OUT_DIM + o] = hv2;
    }
    float ps = acc * wo1, pd = acc * wo2;
#pragma unroll
    for (int m = 16; m >= 1; m >>= 1) {
      ps += __shfl_xor(ps, m, 64);
      pd += __shfl_xor(pd, m, 64);
    }
    if (o == 0) ((float2*)(a_tab + n))[b] = make_float2(ps, pd);
  }
}

// K2 R18: 2 blocks per bin; sort phase unchanged. NEW accumulate phase: each
// wave streams its 4 nodes' records as ONE contiguous range of sorted[]
// (sorted is grouped by nl), routing contributions to 4 register accumulators
// with selector masks — one pipeline drain per wave instead of four.
__global__ __launch_bounds__(256) void accum_kernel(
    const __half2* __restrict__ ezh2, const unsigned int* __restrict__ payload,
    const int* __restrict__ cursor, const float4* __restrict__ a_tab4,
    const float* __restrict__ Watt, const float* __restrict__ batt,
    float* __restrict__ out) {
  __shared__ unsigned int rec[BIN_SLOTS];     // 4 KB
  __shared__ unsigned int sorted[BIN_SLOTS];  // 4 KB
  __shared__ int c8[NCLS];
  __shared__ int hist[NODES_PER_BIN];
  __shared__ int off[NODES_PER_BIN];
  __shared__ int cnt2[NODES_PER_BIN];
  int t = threadIdx.x;
  int bin = blockIdx.x >> 1;
  int half = blockIdx.x & 1;
  if (t < NCLS) {
    int c = cursor[t * NBINS + bin];          // transposed layout
    c8[t] = c > CLS_CAP ? CLS_CAP : (c < 0 ? 0 : c);
  }
  if (t < NODES_PER_BIN) { hist[t] = 0; cnt2[t] = 0; }
  __syncthreads();
  const unsigned int* seg = payload + (size_t)bin * BIN_SLOTS;
  for (int j = t; j < BIN_SLOTS; j += 256) {
    unsigned int r = seg[j];
    rec[j] = r;
    if ((j & (CLS_CAP - 1)) < c8[j >> 7]) atomicAdd(&hist[(r >> 11) & 31], 1);
  }
  __syncthreads();
  if (t < 64) {  // exclusive shuffle scan of 32 counts (wave 0)
    int v = (t < 32) ? hist[t] : 0;
    int orig = v;
#pragma unroll
    for (int d1 = 1; d1 < 32; d1 <<= 1) {
      int x = __shfl_up(v, d1, 64);
      if (t >= d1) v += x;
    }
    if (t < 32) off[t] = v - orig;
  }
  __syncthreads();
  for (int j = t; j < BIN_SLOTS; j += 256) {
    if ((j & (CLS_CAP - 1)) < c8[j >> 7]) {
      unsigned int r = rec[j];
      int nl = (r >> 11) & 31;
      sorted[off[nl] + atomicAdd(&cnt2[nl], 1)] = r;   // total <= 1024: in bounds
    }
  }
  __syncthreads();

  int w = t >> 6, lane = t & 63, o = lane & 31, rr = lane >> 5;
  float wA = Watt[2 * OUT_DIM];
  float bA = batt[0];
  const float kInvQ = 1.0f / 2047.0f;

  int nl0 = half * 16 + w * 4;                // wave's 4 consecutive nodes
  int nbase = bin * NODES_PER_BIN + nl0;
  int base = off[nl0];
  int len = (off[nl0 + 3] + hist[nl0 + 3]) - base;  // contiguous record range
  // per-node a_d values (clamped index: garbage unused since hist==0 there)
  float adx0, ady0, adx1, ady1, adx2, ady2, adx3, ady3;
  {
    int nc0 = nbase     < N_NODES ? nbase     : N_NODES - 1;
    int nc1 = nbase + 1 < N_NODES ? nbase + 1 : N_NODES - 1;
    int nc2 = nbase + 2 < N_NODES ? nbase + 2 : N_NODES - 1;
    int nc3 = nbase + 3 < N_NODES ? nbase + 3 : N_NODES - 1;
    float4 a0 = a_tab4[nc0], a1 = a_tab4[nc1], a2 = a_tab4[nc2], a3 = a_tab4[nc3];
    adx0 = a0.y; ady0 = a0.w; adx1 = a1.y; ady1 = a1.w;
    adx2 = a2.y; ady2 = a2.w; adx3 = a3.y; ady3 = a3.w;
  }
  float2 num0 = {0.f, 0.f}, num1 = {0.f, 0.f}, num2 = {0.f, 0.f}, num3 = {0.f, 0.f};
  float2 den0 = {0.f, 0.f}, den1 = {0.f, 0.f}, den2 = {0.f, 0.f}, den3 = {0.f, 0.f};

#define PROC_REC(r, gate)                                                    \
  {                                                                          \
    int s_ = (int)((r) >> 16);                                               \
    int rel_ = (int)(((r) >> 11) & 31) - nl0;                                \
    __half2 e2_ = ezh2[(size_t)s_ * OUT_DIM + o];                            \
    float4 as_ = a_tab4[s_];                                                 \
    float wt_ = fmaf(((r) & 2047u) * kInvQ, wA, bA);                         \
    float adx_ = rel_ == 0 ? adx0 : rel_ == 1 ? adx1 : rel_ == 2 ? adx2 : adx3; \
    float ady_ = rel_ == 0 ? ady0 : rel_ == 1 ? ady1 : rel_ == 2 ? ady2 : ady3; \
    float l0_ = as_.x + adx_ + wt_;                                          \
    float l1_ = as_.z + ady_ + wt_;                                          \
    l0_ = l0_ > 0.f ? l0_ : 0.01f * l0_;                                     \
    l1_ = l1_ > 0.f ? l1_ : 0.01f * l1_;                                     \
    float2 e_ = __half22float2(e2_);                                         \
    float el0_ = e_.x * l0_ * (gate), el1_ = e_.y * l1_ * (gate);            \
    float ex_ = e_.x * (gate), ey_ = e_.y * (gate);                          \
    float m0_ = rel_ == 0 ? 1.f : 0.f, m1_ = rel_ == 1 ? 1.f : 0.f;          \
    float m2_ = rel_ == 2 ? 1.f : 0.f, m3_ = rel_ == 3 ? 1.f : 0.f;          \
    num0.x = fmaf(m0_, el0_, num0.x); num0.y = fmaf(m0_, el1_, num0.y);      \
    den0.x = fmaf(m0_, ex_, den0.x);  den0.y = fmaf(m0_, ey_, den0.y);       \
    num1.x = fmaf(m1_, el0_, num1.x); num1.y = fmaf(m1_, el1_, num1.y);      \
    den1.x = fmaf(m1_, ex_, den1.x);  den1.y = fmaf(m1_, ey_, den1.y);       \
    num2.x = fmaf(m2_, el0_, num2.x); num2.y = fmaf(m2_, el1_, num2.y);      \
    den2.x = fmaf(m2_, ex_, den2.x);  den2.y = fmaf(m2_, ey_, den2.y);       \
    num3.x = fmaf(m3_, el0_, num3.x); num3.y = fmaf(m3_, el1_, num3.y);      \
    den3.x = fmaf(m3_, ex_, den3.x);  den3.y = fmaf(m3_, ey_, den3.y);       \
  }

  int i = 0;
  for (; i + 3 < len; i += 4) {               // 4 records/wave-iter, 2 in flight/half
    unsigned int rA = sorted[base + i + rr];
    unsigned int rB = sorted[base + i + 2 + rr];
    PROC_REC(rA, 1.f);
    PROC_REC(rB, 1.f);
  }
  for (; i < len; i += 2) {                   // guarded tail (<=3 records)
    int idx = i + rr;
    float g = (idx < len) ? 1.f : 0.f;
    int idxc = (idx < len) ? idx : (len > 0 ? len - 1 : 0);
    unsigned int r = sorted[base + idxc];
    PROC_REC(r, g);
  }
#undef PROC_REC

  // combine half-wave partials and write 4 nodes
  num0.x += __shfl_xor(num0.x, 32, 64); num0.y += __shfl_xor(num0.y, 32, 64);
  den0.x += __shfl_xor(den0.x, 32, 64); den0.y += __shfl_xor(den0.y, 32, 64);
  num1.x += __shfl_xor(num1.x, 32, 64); num1.y += __shfl_xor(num1.y, 32, 64);
  den1.x += __shfl_xor(den1.x, 32, 64); den1.y += __shfl_xor(den1.y, 32, 64);
  num2.x += __shfl_xor(num2.x, 32, 64); num2.y += __shfl_xor(num2.y, 32, 64);
  den2.x += __shfl_xor(den2.x, 32, 64); den2.y += __shfl_xor(den2.y, 32, 64);
  num3.x += __shfl_xor(num3.x, 32, 64); num3.y += __shfl_xor(num3.y, 32, 64);
  den3.x += __shfl_xor(den3.x, 32, 64); den3.y += __shfl_xor(den3.y, 32, 64);
  if (rr == 0) {
#pragma unroll
    for (int k = 0; k < 4; ++k) {
      int n = nbase + k;
      if (n >= N_NODES) break;
      float2 nm = k == 0 ? num0 : k == 1 ? num1 : k == 2 ? num2 : num3;
      float2 dn = k == 0 ? den0 : k == 1 ? den1 : k == 2 ? den2 : den3;
      int cn = hist[nl0 + k];
      float v0 = (cn > 0) ? nm.x / dn.x : 0.f;
      float v1 = (cn > 0) ? nm.y / dn.y : 0.f;
      out[((size_t)0 * N_NODES + n) * OUT_DIM + o] = v0;
      out[((size_t)1 * N_NODES + n) * OUT_DIM + o] = v1;
    }
  }
}

extern "C" void kernel_launch(void* const* d_in, const int* in_sizes, int n_in,
                              void* d_out, int out_size, void* d_ws, size_t ws_size,
                              hipStream_t stream) {
  const float* h      = (const float*)d_in[0];
  const float* weight = (const float*)d_in[1];
  const int*   src    = (const int*)d_in[2];
  const int*   dst    = (const int*)d_in[3];
  const float* Wfc    = (const float*)d_in[4];
  const float* bfc    = (const float*)d_in[5];
  const float* Watt   = (const float*)d_in[6];
  const float* batt   = (const float*)d_in[7];
  float* out = (float*)d_out;

  // workspace (~13.7 MB)
  float4*       a_tab   = (float4*)d_ws;                                  // 800 KB
  unsigned int* payload = (unsigned int*)(a_tab + N_NODES);               // 6.4 MB
  __half2*      ezh2    = (__half2*)(payload + (size_t)NBINS * BIN_SLOTS);// 6.4 MB
  int*          cursor  = (int*)(ezh2 + (size_t)N_NODES * OUT_DIM);       // ~50 KB

  (void)hipMemsetAsync(cursor, 0, NCURS * sizeof(int), stream);
  fused_fc_scatter_kernel<<<SCATTER_BLOCKS + FC_BLOCKS, 256, 0, stream>>>(
      h, Wfc, bfc, Watt, src, dst, weight, ezh2, a_tab, cursor, payload);
  accum_kernel<<<NBINS * 2, 256, 0, stream>>>(ezh2, payload, cursor, a_tab,
                                              Watt, batt, out);
}

// Round 19
// 168.414 us; speedup vs baseline: 1.0985x; 1.0985x over previous
//
#include <hip/hip_runtime.h>
#include <hip/hip_fp16.h>

#define N_NODES 50000
#define N_EDGES 800000
#define IN_DIM  64
#define OUT_DIM 32
#define NODES_PER_BIN 32
#define NBINS   1563                 // ceil(50000/32)
#define NCLS    8
#define CLS_CAP 128                  // per (bin,class): mean 64, +8 sigma; chaining backstops
#define BIN_SLOTS (NCLS * CLS_CAP)   // 1024
#define NCURS   (NBINS * NCLS)       // 12504
#define SCATTER_BLOCKS (N_EDGES / 256)            // 3125 (1 edge/thread)
#define FC_NODES_PER_BLOCK 16
#define FC_BLOCKS (N_NODES / FC_NODES_PER_BLOCK)  // 3125

// physical XCD id (gfx950: HW_REG_XCC_ID = hwreg 20; learn_hip m09)
__device__ __forceinline__ int get_xcc_id() {
  return (int)(__builtin_amdgcn_s_getreg(63508) & 7u);  // 20 | (31<<11)
}

// Fused K1 (R16 config): scatter blocks (1 edge/thread, XCC-id class +
// chaining, TRANSPOSED cursors [cls][bin] so each 64B cursor line is
// single-XCD) then fc blocks (16 nodes/block, W column register-cached).
// ezh2[n*32+o] = {exp(z[n,b0,o]), exp(z[n,b1,o])};  a_tab[n]=(as0,ad0,as1,ad1)
__global__ __launch_bounds__(256) void fused_fc_scatter_kernel(
    const float* __restrict__ h, const float* __restrict__ Wfc,
    const float* __restrict__ bfc, const float* __restrict__ Watt,
    const int* __restrict__ src, const int* __restrict__ dst,
    const float* __restrict__ weight,
    __half2* __restrict__ ezh2, float4* __restrict__ a_tab,
    int* __restrict__ cursor, unsigned int* __restrict__ payload) {
  __shared__ float Wl[IN_DIM * OUT_DIM];                    // 8 KB
  __shared__ float4 hs4[FC_NODES_PER_BLOCK * 2 * 16];       // 8 KB
  int t = threadIdx.x;

  if (blockIdx.x < SCATTER_BLOCKS) {
    int xcc = get_xcc_id();                  // wave-uniform
    int e = blockIdx.x * 256 + t;            // exact coverage
    int s = src[e], d = dst[e];
    float wv = weight[e];
    unsigned int rec = ((unsigned int)s << 16) | ((unsigned int)(d & 31) << 11) |
                       ((unsigned int)__float2int_rn(wv * 2047.0f) & 2047u);
    int bin = d >> 5;
    int c = xcc;
#pragma unroll
    for (int a = 0; a < NCLS; ++a) {
      int pos = atomicAdd(&cursor[c * NBINS + bin], 1);   // XCD-local line
      if (pos < CLS_CAP) {
        payload[(size_t)bin * BIN_SLOTS + c * CLS_CAP + pos] = rec;
        break;
      }
      c = (c + 1) & 7;                       // overflow chain: ~never taken
    }
    return;
  }

  // ---- fc role: 16 nodes per block ----
  int n0 = (blockIdx.x - SCATTER_BLOCKS) * FC_NODES_PER_BLOCK;
  for (int i = t; i < 512; i += 256)
    ((float4*)Wl)[i] = ((const float4*)Wfc)[i];
#pragma unroll
  for (int f = t; f < FC_NODES_PER_BLOCK * 2 * 16; f += 256) {
    int ns = f >> 5, sb = (f >> 4) & 1, i4 = f & 15;
    hs4[f] = ((const float4*)h)[((size_t)sb * N_NODES + (n0 + ns)) * 16 + i4];
  }
  __syncthreads();
  int w = t >> 6, lane = t & 63, o = lane & 31, b = lane >> 5;
  float wreg[IN_DIM];
#pragma unroll
  for (int i = 0; i < IN_DIM; ++i) wreg[i] = Wl[i * OUT_DIM + o];
  float bo = bfc[o];
  float wo1 = Watt[o], wo2 = Watt[OUT_DIM + o];
#pragma unroll
  for (int k = 0; k < 4; ++k) {
    int ns = w * 4 + k;
    int n = n0 + ns;
    float acc = bo;
#pragma unroll
    for (int i4 = 0; i4 < 16; ++i4) {
      float4 hv = hs4[(ns * 2 + b) * 16 + i4];   // wave-broadcast (2 addrs: free)
      acc = fmaf(hv.x, wreg[i4 * 4 + 0], acc);
      acc = fmaf(hv.y, wreg[i4 * 4 + 1], acc);
      acc = fmaf(hv.z, wreg[i4 * 4 + 2], acc);
      acc = fmaf(hv.w, wreg[i4 * 4 + 3], acc);
    }
    float ez = __expf(acc);
    float ezo = __shfl(ez, lane ^ 32, 64);       // partner batch's value
    if (b == 0) {
      __half2 hv2;
      hv2.x = __float2half(ez);
      hv2.y = __float2half(ezo);
      ezh2[(size_t)n * OUT_DIM + o] = hv2;
    }
    float ps = acc * wo1, pd = acc * wo2;
#pragma unroll
    for (int m = 16; m >= 1; m >>= 1) {
      ps += __shfl_xor(ps, m, 64);
      pd += __shfl_xor(pd, m, 64);
    }
    if (o == 0) ((float2*)(a_tab + n))[b] = make_float2(ps, pd);
  }
}

// K2 (R13/R17 measured-best config): 2 blocks per bin; LDS counting sort (int
// atomics), each wave owns 4 nodes; half-wave (rr) record split; half2 ez
// gathers cover both batches per load.
__global__ __launch_bounds__(256) void accum_kernel(
    const __half2* __restrict__ ezh2, const unsigned int* __restrict__ payload,
    const int* __restrict__ cursor, const float4* __restrict__ a_tab4,
    const float* __restrict__ Watt, const float* __restrict__ batt,
    float* __restrict__ out) {
  __shared__ unsigned int rec[BIN_SLOTS];     // 4 KB
  __shared__ unsigned int sorted[BIN_SLOTS];  // 4 KB
  __shared__ int c8[NCLS];
  __shared__ int hist[NODES_PER_BIN];
  __shared__ int off[NODES_PER_BIN];
  __shared__ int cnt2[NODES_PER_BIN];
  int t = threadIdx.x;
  int bin = blockIdx.x >> 1;
  int half = blockIdx.x & 1;
  if (t < NCLS) {
    int c = cursor[t * NBINS + bin];          // transposed layout
    c8[t] = c > CLS_CAP ? CLS_CAP : (c < 0 ? 0 : c);
  }
  if (t < NODES_PER_BIN) { hist[t] = 0; cnt2[t] = 0; }
  __syncthreads();
  const unsigned int* seg = payload + (size_t)bin * BIN_SLOTS;
  for (int j = t; j < BIN_SLOTS; j += 256) {
    unsigned int r = seg[j];
    rec[j] = r;
    if ((j & (CLS_CAP - 1)) < c8[j >> 7]) atomicAdd(&hist[(r >> 11) & 31], 1);
  }
  __syncthreads();
  if (t < 64) {  // exclusive shuffle scan of 32 counts (wave 0)
    int v = (t < 32) ? hist[t] : 0;
    int orig = v;
#pragma unroll
    for (int d1 = 1; d1 < 32; d1 <<= 1) {
      int x = __shfl_up(v, d1, 64);
      if (t >= d1) v += x;
    }
    if (t < 32) off[t] = v - orig;
  }
  __syncthreads();
  for (int j = t; j < BIN_SLOTS; j += 256) {
    if ((j & (CLS_CAP - 1)) < c8[j >> 7]) {
      unsigned int r = rec[j];
      int nl = (r >> 11) & 31;
      sorted[off[nl] + atomicAdd(&cnt2[nl], 1)] = r;   // total <= 1024: in bounds
    }
  }
  __syncthreads();

  int w = t >> 6, lane = t & 63, o = lane & 31, rr = lane >> 5;
  float wA = Watt[2 * OUT_DIM];
  float bA = batt[0];
  const float kInvQ = 1.0f / 2047.0f;
#pragma unroll
  for (int k = 0; k < 4; ++k) {
    int nl = half * 16 + w * 4 + k;             // wave-uniform
    int n = bin * NODES_PER_BIN + nl;
    if (n >= N_NODES) break;
    int cn = hist[nl];
    int base = off[nl];
    float4 an = a_tab4[n];
    float adx = an.y, ady = an.w;               // a_d(n,b0), a_d(n,b1)
    float2 num = make_float2(0.f, 0.f), den = make_float2(0.f, 0.f);
    int i = 0;
    for (; i + 3 < cn; i += 4) {                // 2 records per half-wave iter
      unsigned int rA = sorted[base + i + rr];
      unsigned int rB = sorted[base + i + 2 + rr];
      int sA = rA >> 16, sB = rB >> 16;
      __half2 eA2 = ezh2[(size_t)sA * OUT_DIM + o];
      __half2 eB2 = ezh2[(size_t)sB * OUT_DIM + o];
      float4 aA = a_tab4[sA];
      float4 aB = a_tab4[sB];
      float wtA = fmaf((rA & 2047u) * kInvQ, wA, bA);
      float wtB = fmaf((rB & 2047u) * kInvQ, wA, bA);
      float l0A = aA.x + adx + wtA, l1A = aA.z + ady + wtA;
      float l0B = aB.x + adx + wtB, l1B = aB.z + ady + wtB;
      l0A = l0A > 0.f ? l0A : 0.01f * l0A;
      l1A = l1A > 0.f ? l1A : 0.01f * l1A;
      l0B = l0B > 0.f ? l0B : 0.01f * l0B;
      l1B = l1B > 0.f ? l1B : 0.01f * l1B;
      float2 eA = __half22float2(eA2);
      float2 eB = __half22float2(eB2);
      num.x = fmaf(eA.x, l0A, num.x); num.y = fmaf(eA.y, l1A, num.y);
      den.x += eA.x;                  den.y += eA.y;
      num.x = fmaf(eB.x, l0B, num.x); num.y = fmaf(eB.y, l1B, num.y);
      den.x += eB.x;                  den.y += eB.y;
    }
    for (; i < cn; i += 2) {                    // guarded tail
      int idx = i + rr;
      float m = (idx < cn) ? 1.f : 0.f;
      int idxc = (idx < cn) ? idx : cn - 1;
      unsigned int r = sorted[base + idxc];
      int s = r >> 16;
      __half2 e2 = ezh2[(size_t)s * OUT_DIM + o];
      float4 as4 = a_tab4[s];
      float wt = fmaf((r & 2047u) * kInvQ, wA, bA);
      float l0 = as4.x + adx + wt, l1 = as4.z + ady + wt;
      l0 = l0 > 0.f ? l0 : 0.01f * l0;
      l1 = l1 > 0.f ? l1 : 0.01f * l1;
      float2 e = __half22float2(e2);
      e.x *= m; e.y *= m;
      num.x = fmaf(e.x, l0, num.x); num.y = fmaf(e.y, l1, num.y);
      den.x += e.x;                 den.y += e.y;
    }
    num.x += __shfl_xor(num.x, 32, 64);
    num.y += __shfl_xor(num.y, 32, 64);
    den.x += __shfl_xor(den.x, 32, 64);
    den.y += __shfl_xor(den.y, 32, 64);
    if (rr == 0) {
      float v0 = (cn > 0) ? num.x / den.x : 0.f;
      float v1 = (cn > 0) ? num.y / den.y : 0.f;
      out[((size_t)0 * N_NODES + n) * OUT_DIM + o] = v0;
      out[((size_t)1 * N_NODES + n) * OUT_DIM + o] = v1;
    }
  }
}

extern "C" void kernel_launch(void* const* d_in, const int* in_sizes, int n_in,
                              void* d_out, int out_size, void* d_ws, size_t ws_size,
                              hipStream_t stream) {
  const float* h      = (const float*)d_in[0];
  const float* weight = (const float*)d_in[1];
  const int*   src    = (const int*)d_in[2];
  const int*   dst    = (const int*)d_in[3];
  const float* Wfc    = (const float*)d_in[4];
  const float* bfc    = (const float*)d_in[5];
  const float* Watt   = (const float*)d_in[6];
  const float* batt   = (const float*)d_in[7];
  float* out = (float*)d_out;

  // workspace (~13.7 MB)
  float4*       a_tab   = (float4*)d_ws;                                  // 800 KB
  unsigned int* payload = (unsigned int*)(a_tab + N_NODES);               // 6.4 MB
  __half2*      ezh2    = (__half2*)(payload + (size_t)NBINS * BIN_SLOTS);// 6.4 MB
  int*          cursor  = (int*)(ezh2 + (size_t)N_NODES * OUT_DIM);       // ~50 KB

  (void)hipMemsetAsync(cursor, 0, NCURS * sizeof(int), stream);
  fused_fc_scatter_kernel<<<SCATTER_BLOCKS + FC_BLOCKS, 256, 0, stream>>>(
      h, Wfc, bfc, Watt, src, dst, weight, ezh2, a_tab, cursor, payload);
  accum_kernel<<<NBINS * 2, 256, 0, stream>>>(ezh2, payload, cursor, a_tab,
                                              Watt, batt, out);
}